// Round 1
// baseline (61.104 us; speedup 1.0000x reference)
//
#include <hip/hip_runtime.h>
#include <hip/hip_bf16.h>

#define B_SZ 1024
#define F_SZ 2048
#define NK   32
#define KD   8
#define NCOL (NK * KD)      // 256
#define OUTF (F_SZ + NK)    // 2080

// ---------------------------------------------------------------------------
// Kernel 1: split-K fp32 GEMM partials.  m_part[ks][i][n] = x[i, ksK:(ks+1)K] . W[...,n]
// Tile: 128 rows x 64 cols per block, 256 threads, 8x4 outputs per thread.
// grid = 8 mtiles * 4 ntiles * KS
// ---------------------------------------------------------------------------
__global__ __launch_bounds__(256) void gemm_partial_kernel(
    const float* __restrict__ x, const float* __restrict__ W,
    float* __restrict__ part, int KS) {
  int b  = blockIdx.x;
  int mt = b & 7;          // 8 m-tiles of 128
  int nt = (b >> 3) & 3;   // 4 n-tiles of 64
  int ks = b >> 5;         // K-chunk id
  int KC = F_SZ / KS;
  int i0 = mt * 128, n0 = nt * 64, k0 = ks * KC;

  __shared__ float xs[16][128];   // [kk][row]
  __shared__ float wsd[16][64];   // [kk][col]

  int t = threadIdx.x;
  // staging indices
  int sr  = t >> 1;         // 0..127 (row)
  int skq = (t & 1) * 8;    // k offset 0 or 8
  int wkk = t >> 4;         // 0..15
  int wc4 = (t & 15) * 4;   // 0..60
  // compute indices
  int tr = t >> 4;          // 0..15 -> 8 rows each
  int tc = t & 15;          // 0..15 -> 4 cols each
  int r0 = tr * 8, c0 = tc * 4;

  float acc[8][4];
#pragma unroll
  for (int rr = 0; rr < 8; ++rr)
#pragma unroll
    for (int cc = 0; cc < 4; ++cc) acc[rr][cc] = 0.f;

  for (int kk0 = 0; kk0 < KC; kk0 += 16) {
    // load staging data to registers first
    const float4* xp = reinterpret_cast<const float4*>(
        &x[(size_t)(i0 + sr) * F_SZ + k0 + kk0 + skq]);
    float4 xa = xp[0];
    float4 xb = xp[1];
    float4 wv = *reinterpret_cast<const float4*>(
        &W[(size_t)(k0 + kk0 + wkk) * NCOL + n0 + wc4]);

    __syncthreads();  // previous compute done before overwriting LDS
    xs[skq + 0][sr] = xa.x; xs[skq + 1][sr] = xa.y;
    xs[skq + 2][sr] = xa.z; xs[skq + 3][sr] = xa.w;
    xs[skq + 4][sr] = xb.x; xs[skq + 5][sr] = xb.y;
    xs[skq + 6][sr] = xb.z; xs[skq + 7][sr] = xb.w;
    *reinterpret_cast<float4*>(&wsd[wkk][wc4]) = wv;
    __syncthreads();

#pragma unroll
    for (int kk = 0; kk < 16; ++kk) {
      float a[8], bb[4];
      *reinterpret_cast<float4*>(&a[0]) = *reinterpret_cast<const float4*>(&xs[kk][r0]);
      *reinterpret_cast<float4*>(&a[4]) = *reinterpret_cast<const float4*>(&xs[kk][r0 + 4]);
      *reinterpret_cast<float4*>(&bb[0]) = *reinterpret_cast<const float4*>(&wsd[kk][c0]);
#pragma unroll
      for (int rr = 0; rr < 8; ++rr)
#pragma unroll
        for (int cc = 0; cc < 4; ++cc)
          acc[rr][cc] = fmaf(a[rr], bb[cc], acc[rr][cc]);
    }
  }

  float* dst = part + (size_t)ks * B_SZ * NCOL;
#pragma unroll
  for (int rr = 0; rr < 8; ++rr) {
    float4 v = make_float4(acc[rr][0], acc[rr][1], acc[rr][2], acc[rr][3]);
    *reinterpret_cast<float4*>(&dst[(size_t)(i0 + r0 + rr) * NCOL + n0 + c0]) = v;
  }
}

// ---------------------------------------------------------------------------
// Kernel 2: reduce K-split partials -> m[1024][256]
// ---------------------------------------------------------------------------
__global__ __launch_bounds__(256) void reduce_m_kernel(
    const float* __restrict__ part, float* __restrict__ m, int KS) {
  int idx = blockIdx.x * 256 + threadIdx.x;  // float4 index, 65536 total
  const float4* p4 = reinterpret_cast<const float4*>(part);
  float4 s = make_float4(0.f, 0.f, 0.f, 0.f);
  for (int ks = 0; ks < KS; ++ks) {
    float4 v = p4[(size_t)ks * (B_SZ * NCOL / 4) + idx];
    s.x += v.x; s.y += v.y; s.z += v.z; s.w += v.w;
  }
  reinterpret_cast<float4*>(m)[idx] = s;
}

// ---------------------------------------------------------------------------
// Kernel 3: pairwise L1 + exp partial sums.
// grid = 32 i-tiles * 8 j-chunks, block = 512.
// thread t: k = t&31, owns 2 rows; loops 128 j.  m reads are L1/L2-served
// (m = 1 MB total; low 32 lanes of each wave read a contiguous 1 KB row).
// mbp[bj][i][k] = sum_{j in chunk} exp(-L1(m[i,k,:], m[j,k,:]))
// ---------------------------------------------------------------------------
__global__ __launch_bounds__(512) void pairwise_kernel(
    const float* __restrict__ m, float* __restrict__ mbp) {
  int bi = blockIdx.x & 31;   // i-tile
  int bj = blockIdx.x >> 5;   // j-chunk 0..7
  int t = threadIdx.x;
  int k = t & 31;
  int g = t >> 5;             // 0..15
  int i0 = bi * 32 + g * 2;
  int j0 = bj * 128;

  const float4* mv = reinterpret_cast<const float4*>(m);  // m[i][c]: idx = i*64 + c4
  float4 a0 = mv[(size_t)i0 * 64 + k * 2];
  float4 a1 = mv[(size_t)i0 * 64 + k * 2 + 1];
  float4 b0 = mv[(size_t)(i0 + 1) * 64 + k * 2];
  float4 b1 = mv[(size_t)(i0 + 1) * 64 + k * 2 + 1];

  float acc0 = 0.f, acc1 = 0.f;
#pragma unroll 4
  for (int jj = 0; jj < 128; ++jj) {
    int j = j0 + jj;
    float4 c0 = mv[(size_t)j * 64 + k * 2];
    float4 c1 = mv[(size_t)j * 64 + k * 2 + 1];
    float s0 = fabsf(a0.x - c0.x) + fabsf(a0.y - c0.y) +
               fabsf(a0.z - c0.z) + fabsf(a0.w - c0.w) +
               fabsf(a1.x - c1.x) + fabsf(a1.y - c1.y) +
               fabsf(a1.z - c1.z) + fabsf(a1.w - c1.w);
    float s1 = fabsf(b0.x - c0.x) + fabsf(b0.y - c0.y) +
               fabsf(b0.z - c0.z) + fabsf(b0.w - c0.w) +
               fabsf(b1.x - c1.x) + fabsf(b1.y - c1.y) +
               fabsf(b1.z - c1.z) + fabsf(b1.w - c1.w);
    acc0 += __expf(-s0);
    acc1 += __expf(-s1);
  }
  mbp[((size_t)bj * B_SZ + i0) * NK + k]     = acc0;
  mbp[((size_t)bj * B_SZ + i0 + 1) * NK + k] = acc1;
}

// ---------------------------------------------------------------------------
// Kernel 4: finalize: out[i] = concat(x[i], sum_bj mbp[bj][i][:])
// grid = 1024 (one row per block), block = 256
// ---------------------------------------------------------------------------
__global__ __launch_bounds__(256) void finalize_kernel(
    const float* __restrict__ x, const float* __restrict__ mbp,
    float* __restrict__ out) {
  int i = blockIdx.x;
  int t = threadIdx.x;
  const float4* xr = reinterpret_cast<const float4*>(x + (size_t)i * F_SZ);
  float4* orow = reinterpret_cast<float4*>(out + (size_t)i * OUTF);  // 8320B row base, 16B aligned
  orow[t]       = xr[t];
  orow[t + 256] = xr[t + 256];
  if (t < NK) {
    float s = 0.f;
#pragma unroll
    for (int c = 0; c < 8; ++c) s += mbp[((size_t)c * B_SZ + i) * NK + t];
    out[(size_t)i * OUTF + F_SZ + t] = s;
  }
}

extern "C" void kernel_launch(void* const* d_in, const int* in_sizes, int n_in,
                              void* d_out, int out_size, void* d_ws, size_t ws_size,
                              hipStream_t stream) {
  const float* x = (const float*)d_in[0];
  const float* W = (const float*)d_in[1];
  float* out = (float*)d_out;
  char* ws = (char*)d_ws;

  const size_t MB = 1u << 20;
  // pick K-split that fits workspace: need m(1MB) + part(KS MB) + mbp(1MB)
  int KS = 8;
  while (KS > 1 && ws_size < MB * (size_t)(2 + KS)) KS >>= 1;

  float* m    = (float*)ws;                         // 1 MB
  float* part = (float*)(ws + MB);                  // KS MB
  float* mbp  = (float*)(ws + MB + (size_t)KS * MB); // 1 MB

  gemm_partial_kernel<<<dim3(8 * 4 * KS), 256, 0, stream>>>(x, W, part, KS);
  reduce_m_kernel<<<dim3(256), 256, 0, stream>>>(part, m, KS);
  pairwise_kernel<<<dim3(256), 512, 0, stream>>>(m, mbp);
  finalize_kernel<<<dim3(B_SZ), 256, 0, stream>>>(x, mbp, out);
}

// Round 2
// 52.829 us; speedup vs baseline: 1.1566x; 1.1566x over previous
//
#include <hip/hip_runtime.h>
#include <hip/hip_bf16.h>

#define B_SZ 1024
#define F_SZ 2048
#define NK   32
#define KD   8
#define NCOL 256            // NK*KD
#define OUTF 2080           // F + NK
#define KS   4              // GEMM split-K

typedef __attribute__((ext_vector_type(8))) short short8v;
typedef __attribute__((ext_vector_type(8))) unsigned short ushort8v;
typedef __attribute__((ext_vector_type(4))) unsigned short ushort4v;
typedef __attribute__((ext_vector_type(4))) float f32x4;

static __device__ __forceinline__ unsigned short f2bf(float v) {
  __hip_bfloat16 h = __float2bfloat16(v);   // RNE
  return reinterpret_cast<unsigned short&>(h);
}

// ---------------------------------------------------------------------------
// Kernel 1: convert x -> bf16 AND copy x rows into out (fuses old finalize copy).
// grid 2048 x 256; one float4 per thread.
// ---------------------------------------------------------------------------
__global__ __launch_bounds__(256) void convert_x_kernel(
    const float* __restrict__ x, unsigned short* __restrict__ xbf,
    float* __restrict__ out) {
  int idx = blockIdx.x * 256 + threadIdx.x;     // float4 id, 524288 total
  int flat = idx * 4;
  int i = flat >> 11;            // row
  int c = flat & 2047;           // col
  float4 v = reinterpret_cast<const float4*>(x)[idx];
  *reinterpret_cast<float4*>(&out[(size_t)i * OUTF + c]) = v;
  ushort4v u;
  u[0] = f2bf(v.x); u[1] = f2bf(v.y); u[2] = f2bf(v.z); u[3] = f2bf(v.w);
  *reinterpret_cast<ushort4v*>(&xbf[(size_t)idx * 4]) = u;
}

// ---------------------------------------------------------------------------
// Kernel 2: W[2048][256] f32 -> Wt[256][2048] bf16 (k-contiguous rows).
// 64x64 LDS tile transpose; grid 32 k-tiles * 4 n-tiles = 128 blocks.
// ---------------------------------------------------------------------------
__global__ __launch_bounds__(256) void transpose_W_kernel(
    const float* __restrict__ W, unsigned short* __restrict__ wt) {
  __shared__ unsigned short tile[64][66];   // [k][n], pad to dodge conflicts
  int b = blockIdx.x;
  int kt = b & 31, nt = b >> 5;
  int k0 = kt * 64, n0 = nt * 64;
  int t = threadIdx.x;
  int r  = t >> 2;           // 0..63
  int c0 = (t & 3) * 16;
#pragma unroll
  for (int u = 0; u < 4; ++u) {
    float4 v = *reinterpret_cast<const float4*>(&W[(size_t)(k0 + r) * NCOL + n0 + c0 + 4 * u]);
    tile[r][c0 + 4 * u + 0] = f2bf(v.x);
    tile[r][c0 + 4 * u + 1] = f2bf(v.y);
    tile[r][c0 + 4 * u + 2] = f2bf(v.z);
    tile[r][c0 + 4 * u + 3] = f2bf(v.w);
  }
  __syncthreads();
  int n  = t >> 2;           // 0..63 (output row in Wt)
  int kq = (t & 3) * 16;
  ushort8v o0, o1;
#pragma unroll
  for (int u = 0; u < 8; ++u) o0[u] = tile[kq + u][n];
#pragma unroll
  for (int u = 0; u < 8; ++u) o1[u] = tile[kq + 8 + u][n];
  unsigned short* dst = &wt[(size_t)(n0 + n) * F_SZ + k0 + kq];
  *reinterpret_cast<ushort8v*>(dst)     = o0;
  *reinterpret_cast<ushort8v*>(dst + 8) = o1;
}

// ---------------------------------------------------------------------------
// Kernel 3: bf16 MFMA GEMM partials.  part[ks][i][n] = x[i, chunk].W[chunk, n]
// BM=128 BN=64 BK=32, 256 thr (4 waves 2x2, wave tile 64x32 = 4x2 frags).
// grid = 8 mt * 4 nt * KS
// ---------------------------------------------------------------------------
__global__ __launch_bounds__(256) void mfma_gemm_kernel(
    const unsigned short* __restrict__ xbf, const unsigned short* __restrict__ wt,
    float* __restrict__ part) {
  __shared__ __align__(16) unsigned short As[128][40];  // [row][k], +8 pad
  __shared__ __align__(16) unsigned short Bs[64][40];   // [col(n)][k]

  int b = blockIdx.x;
  int mt = b & 7, nt = (b >> 3) & 3, ks = b >> 5;
  int i0 = mt * 128, n0 = nt * 64, kbase = ks * (F_SZ / KS);

  int t = threadIdx.x;
  int w = t >> 6, l = t & 63;
  int wr = w >> 1, wc = w & 1;      // wave grid 2x2
  int hi = l >> 4, r16 = l & 15;

  int arow = t >> 1, akq = (t & 1) * 16;   // A staging: 2 x ushort8 / thread
  int brow = t >> 2, bkq = (t & 3) * 8;    // B staging: 1 x ushort8 / thread

  f32x4 acc[4][2];
#pragma unroll
  for (int mi = 0; mi < 4; ++mi)
#pragma unroll
    for (int ni = 0; ni < 2; ++ni) acc[mi][ni] = (f32x4)(0.f);

  for (int kk = 0; kk < F_SZ / KS; kk += 32) {
    const unsigned short* ap = &xbf[(size_t)(i0 + arow) * F_SZ + kbase + kk + akq];
    ushort8v a0 = *reinterpret_cast<const ushort8v*>(ap);
    ushort8v a1 = *reinterpret_cast<const ushort8v*>(ap + 8);
    ushort8v b0 = *reinterpret_cast<const ushort8v*>(
        &wt[(size_t)(n0 + brow) * F_SZ + kbase + kk + bkq]);
    __syncthreads();   // previous iter's reads done before overwrite
    *reinterpret_cast<ushort8v*>(&As[arow][akq])     = a0;
    *reinterpret_cast<ushort8v*>(&As[arow][akq + 8]) = a1;
    *reinterpret_cast<ushort8v*>(&Bs[brow][bkq])     = b0;
    __syncthreads();

    short8v af[4], bfr[2];
#pragma unroll
    for (int mi = 0; mi < 4; ++mi)
      af[mi] = *reinterpret_cast<const short8v*>(&As[wr * 64 + mi * 16 + r16][hi * 8]);
#pragma unroll
    for (int ni = 0; ni < 2; ++ni)
      bfr[ni] = *reinterpret_cast<const short8v*>(&Bs[wc * 32 + ni * 16 + r16][hi * 8]);
#pragma unroll
    for (int mi = 0; mi < 4; ++mi)
#pragma unroll
      for (int ni = 0; ni < 2; ++ni)
        acc[mi][ni] = __builtin_amdgcn_mfma_f32_16x16x32_bf16(
            af[mi], bfr[ni], acc[mi][ni], 0, 0, 0);
  }

  float* dst = part + (size_t)ks * B_SZ * NCOL;
#pragma unroll
  for (int mi = 0; mi < 4; ++mi)
#pragma unroll
    for (int ni = 0; ni < 2; ++ni)
#pragma unroll
      for (int r = 0; r < 4; ++r) {
        int gi = i0 + wr * 64 + mi * 16 + hi * 4 + r;   // D row
        int gn = n0 + wc * 32 + ni * 16 + r16;          // D col
        dst[(size_t)gi * NCOL + gn] = acc[mi][ni][r];
      }
}

// ---------------------------------------------------------------------------
// Kernel 4: reduce split-K partials -> m[1024][256] f32
// ---------------------------------------------------------------------------
__global__ __launch_bounds__(256) void reduce_m_kernel(
    const float* __restrict__ part, float* __restrict__ m) {
  int idx = blockIdx.x * 256 + threadIdx.x;  // float4 id, 65536 total
  const float4* p4 = reinterpret_cast<const float4*>(part);
  float4 s = make_float4(0.f, 0.f, 0.f, 0.f);
#pragma unroll
  for (int ks = 0; ks < KS; ++ks) {
    float4 v = p4[(size_t)ks * (B_SZ * NCOL / 4) + idx];
    s.x += v.x; s.y += v.y; s.z += v.z; s.w += v.w;
  }
  reinterpret_cast<float4*>(m)[idx] = s;
}

// ---------------------------------------------------------------------------
// Kernel 5: pairwise L1 + exp partial sums (unchanged from R1 — VALU-bound,
// m is 1 MB = L1/L2-resident, no LDS staging needed).
// mbp[bj][i][k] = sum_{j in chunk bj} exp(-L1(m[i,k,:], m[j,k,:]))
// ---------------------------------------------------------------------------
__global__ __launch_bounds__(512) void pairwise_kernel(
    const float* __restrict__ m, float* __restrict__ mbp) {
  int bi = blockIdx.x & 31;
  int bj = blockIdx.x >> 5;
  int t = threadIdx.x;
  int k = t & 31;
  int g = t >> 5;
  int i0 = bi * 32 + g * 2;
  int j0 = bj * 128;

  const float4* mv = reinterpret_cast<const float4*>(m);
  float4 a0 = mv[(size_t)i0 * 64 + k * 2];
  float4 a1 = mv[(size_t)i0 * 64 + k * 2 + 1];
  float4 b0 = mv[(size_t)(i0 + 1) * 64 + k * 2];
  float4 b1 = mv[(size_t)(i0 + 1) * 64 + k * 2 + 1];

  float acc0 = 0.f, acc1 = 0.f;
#pragma unroll 4
  for (int jj = 0; jj < 128; ++jj) {
    int j = j0 + jj;
    float4 c0 = mv[(size_t)j * 64 + k * 2];
    float4 c1 = mv[(size_t)j * 64 + k * 2 + 1];
    float s0 = fabsf(a0.x - c0.x) + fabsf(a0.y - c0.y) +
               fabsf(a0.z - c0.z) + fabsf(a0.w - c0.w) +
               fabsf(a1.x - c1.x) + fabsf(a1.y - c1.y) +
               fabsf(a1.z - c1.z) + fabsf(a1.w - c1.w);
    float s1 = fabsf(b0.x - c0.x) + fabsf(b0.y - c0.y) +
               fabsf(b0.z - c0.z) + fabsf(b0.w - c0.w) +
               fabsf(b1.x - c1.x) + fabsf(b1.y - c1.y) +
               fabsf(b1.z - c1.z) + fabsf(b1.w - c1.w);
    acc0 += __expf(-s0);
    acc1 += __expf(-s1);
  }
  mbp[((size_t)bj * B_SZ + i0) * NK + k]     = acc0;
  mbp[((size_t)bj * B_SZ + i0 + 1) * NK + k] = acc1;
}

// ---------------------------------------------------------------------------
// Kernel 6: out[i][2048+k] = sum over 8 j-chunks of mbp
// ---------------------------------------------------------------------------
__global__ __launch_bounds__(256) void finalize_mb_kernel(
    const float* __restrict__ mbp, float* __restrict__ out) {
  int idx = blockIdx.x * 256 + threadIdx.x;   // 32768 total
  int i = idx >> 5, k = idx & 31;
  float s = 0.f;
#pragma unroll
  for (int c = 0; c < 8; ++c) s += mbp[((size_t)c * B_SZ + i) * NK + k];
  out[(size_t)i * OUTF + F_SZ + k] = s;
}

extern "C" void kernel_launch(void* const* d_in, const int* in_sizes, int n_in,
                              void* d_out, int out_size, void* d_ws, size_t ws_size,
                              hipStream_t stream) {
  const float* x = (const float*)d_in[0];
  const float* W = (const float*)d_in[1];
  float* out = (float*)d_out;
  char* ws = (char*)d_ws;

  const size_t MB = 1u << 20;
  unsigned short* xbf = (unsigned short*)ws;                 // 4 MB
  unsigned short* wt  = (unsigned short*)(ws + 4 * MB);      // 1 MB
  float* part = (float*)(ws + 5 * MB);                       // KS MB (4)
  float* m    = (float*)(ws + 9 * MB);                       // 1 MB
  float* mbp  = (float*)(ws + 10 * MB);                      // 1 MB

  convert_x_kernel<<<dim3(2048), 256, 0, stream>>>(x, xbf, out);
  transpose_W_kernel<<<dim3(128), 256, 0, stream>>>(W, wt);
  mfma_gemm_kernel<<<dim3(8 * 4 * KS), 256, 0, stream>>>(xbf, wt, part);
  reduce_m_kernel<<<dim3(256), 256, 0, stream>>>(part, m);
  pairwise_kernel<<<dim3(256), 512, 0, stream>>>(m, mbp);
  finalize_mb_kernel<<<dim3(128), 256, 0, stream>>>(mbp, out);
}